// Round 1
// baseline (235.986 us; speedup 1.0000x reference)
//
#include <hip/hip_runtime.h>
#include <math.h>

#define SEQ_LENGTH 4096
#define D_MODEL   2048
#define BATCH     32

typedef float f4 __attribute__((ext_vector_type(4)));

// Output [B, S, D] with pe[s, 2i] = sin(theta), pe[s, 2i+1] = cos(theta),
// theta = s / 10000^(2i/D). Output is independent of the token-id input.
//
// One thread computes one float4 of the [S, D] table (= 2 (sin,cos) pairs)
// and broadcasts it to all 32 batch copies (stores are coalesced per batch).
__global__ __launch_bounds__(256) void PositionalEncoding_54915451847173_kernel(
    float* __restrict__ out) {
    const int t  = blockIdx.x * blockDim.x + threadIdx.x;  // 0 .. S*D/4 - 1
    const int jj = t & (D_MODEL / 4 - 1);                  // float4 idx in row, 0..511
    const int s  = t >> 9;                                 // seq position (D/4 = 512)

    const float pos = (float)s;
    // pair indices handled by this thread: i0 = 2*jj, i1 = 2*jj + 1 (i in [0, D/2))
    const float fi0 = (float)(2 * jj);
    const float fi1 = (float)(2 * jj + 1);

    // inv_freq = 10000^(-2i/D) = exp2(-(2i/D) * log2(10000))
    const float c  = -(2.0f / (float)D_MODEL) * 13.28771237954945f;  // -log2(1e4)*2/D
    const float f0 = exp2f(c * fi0);
    const float f1 = exp2f(c * fi1);

    const float th0 = pos * f0;
    const float th1 = pos * f1;

    // Range-reduce to [0,1) revolutions, then native HW sin/cos on a small arg.
    const float inv2pi = 0.15915494309189535f;
    const float twopi  = 6.283185307179586f;
    float r0 = th0 * inv2pi; r0 -= floorf(r0);
    float r1 = th1 * inv2pi; r1 -= floorf(r1);
    const float a0 = r0 * twopi;
    const float a1 = r1 * twopi;

    f4 v;
    v.x = __sinf(a0);
    v.y = __cosf(a0);
    v.z = __sinf(a1);
    v.w = __cosf(a1);

    f4* p = (f4*)out + t;  // batch-0 slot; batches are S*D/4 float4s apart
    #pragma unroll
    for (int b = 0; b < BATCH; ++b) {
        __builtin_nontemporal_store(v, p);
        p += SEQ_LENGTH * (D_MODEL / 4);
    }
}

extern "C" void kernel_launch(void* const* d_in, const int* in_sizes, int n_in,
                              void* d_out, int out_size, void* d_ws, size_t ws_size,
                              hipStream_t stream) {
    (void)d_in; (void)in_sizes; (void)n_in; (void)d_ws; (void)ws_size; (void)out_size;
    float* out = (float*)d_out;
    const int total_f4 = SEQ_LENGTH * (D_MODEL / 4);       // 2,097,152 threads
    const int block = 256;
    const int grid  = total_f4 / block;                    // 8192 blocks
    PositionalEncoding_54915451847173_kernel<<<grid, block, 0, stream>>>(out);
}